// Round 1
// baseline (632.607 us; speedup 1.0000x reference)
//
#include <hip/hip_runtime.h>

#define BINS 10

// R5: replace the 10-bin compare/select chain (30 VALU + 20 SALU per element,
// with v_cmp->sgpr->cndmask hazard padding) by a per-lane-column LDS histogram:
// 2 LDS atomics + ~6 VALU per element. hist layout [BINS][64]: lane l hits
// bank (l mod 32) -> only the free 2-way aliasing; counts stay exact (u32).
// Load structure (8 interleaved dwordx4 + sched fence) is unchanged from R4.

__device__ __forceinline__ void elem(float p, float t, int lane,
                                     float* __restrict__ hs,
                                     unsigned int* __restrict__ hc)
{
    float g  = fabsf(p - t);
    float l2 = __log2f(1.0f - g);     // bce = -ln2 * log2(1-g); fold -ln2 later
    int   bi = (int)(g * 10.0f);      // g in (0.01,0.99): bi in [0,9], no clamp
    int  idx = (bi << 6) + lane;      // byte addr = (bi<<8) + lane*4 + base
    atomicAdd(hs + idx, l2);          // ds_add_f32 (no return)
    atomicAdd(hc + idx, 1u);          // ds_add_u32 (exact)
}

__device__ __forceinline__ void proc4v(const float4 p, const float4 t, int lane,
                                       float* __restrict__ hs,
                                       unsigned int* __restrict__ hc)
{
    elem(p.x, t.x, lane, hs, hc); elem(p.y, t.y, lane, hs, hc);
    elem(p.z, t.z, lane, hs, hc); elem(p.w, t.w, lane, hs, hc);
}

__global__ __launch_bounds__(256, 4) void ghm_partial(
    const float4* __restrict__ p4,
    const float4* __restrict__ t4,
    float* __restrict__ gsum,          // [BINS] floats in d_ws
    unsigned int* __restrict__ gcnt,   // [BINS] uints in d_ws
    int n4)
{
    __shared__ float        hsum[BINS * 64];   // 2.5 KB
    __shared__ unsigned int hcnt[BINS * 64];   // 2.5 KB

    const int tid  = threadIdx.x;
    const int lane = tid & 63;

    for (int k = tid; k < BINS * 64; k += blockDim.x) {
        hsum[k] = 0.0f;
        hcnt[k] = 0u;
    }
    __syncthreads();

    const int start  = blockIdx.x * blockDim.x + tid;
    const int stride = gridDim.x * blockDim.x;
    const int ngrp   = n4 / (4 * stride);   // 4 at 2048x256, n4 = 2^23

    // Bulk-load groups: 8 interleaved dwordx4 loads (128 B/thread in flight),
    // then a scheduling fence so the compiler cannot sink loads into compute.
    int i = start;
    for (int grp = 0; grp < ngrp; ++grp, i += 4 * stride) {
        float4 P0 = p4[i];
        float4 T0 = t4[i];
        float4 P1 = p4[i + stride];
        float4 T1 = t4[i + stride];
        float4 P2 = p4[i + 2 * stride];
        float4 T2 = t4[i + 2 * stride];
        float4 P3 = p4[i + 3 * stride];
        float4 T3 = t4[i + 3 * stride];
        __builtin_amdgcn_sched_barrier(0);  // loads above, compute below
        proc4v(P0, T0, lane, hsum, hcnt);
        proc4v(P1, T1, lane, hsum, hcnt);
        proc4v(P2, T2, lane, hsum, hcnt);
        proc4v(P3, T3, lane, hsum, hcnt);
    }
    // tail: any remaining float4s (n4 not divisible by 4*stride)
    for (int j = start + ngrp * 4 * stride; j < n4; j += stride) {
        float4 p = p4[j], t = t4[j];
        proc4v(p, t, lane, hsum, hcnt);
    }

    __syncthreads();   // all waves' ds_adds visible

    // -------- epilogue: wave 0 reduces [BINS][64] -> one global atomic/bin --
    if (tid < 64) {
#pragma unroll
        for (int b = 0; b < BINS; ++b) {
            float        s = hsum[(b << 6) + lane];
            unsigned int c = hcnt[(b << 6) + lane];
#pragma unroll
            for (int off = 32; off > 0; off >>= 1) {
                s += __shfl_down(s, off);
                c += __shfl_down(c, off);
            }
            if (lane == 0) {
                atomicAdd(&gsum[b], s);
                atomicAdd(&gcnt[b], c);
            }
        }
    }
}

__global__ void ghm_finalize(const float* __restrict__ gsum,
                             const unsigned int* __restrict__ gcnt,
                             float* __restrict__ out)
{
    if (threadIdx.x == 0 && blockIdx.x == 0) {
        int n = 0;
#pragma unroll
        for (int b = 0; b < BINS; ++b) n += (gcnt[b] > 0u) ? 1 : 0;
        float nn = (float)(n > 0 ? n : 1);
        float acc = 0.0f;
#pragma unroll
        for (int b = 0; b < BINS; ++b) {
            if (gcnt[b] > 0u)
                acc += gsum[b] / ((float)gcnt[b] * nn);  // counts < 2^24: exact
        }
        out[0] = -0.6931471805599453f * acc;   // fold -ln(2) from log2 domain
    }
}

extern "C" void kernel_launch(void* const* d_in, const int* in_sizes, int n_in,
                              void* d_out, int out_size, void* d_ws, size_t ws_size,
                              hipStream_t stream)
{
    const float* p = (const float*)d_in[0];   // inputs (probabilities)
    const float* t = (const float*)d_in[1];   // targets (0/1 floats)
    const int n  = in_sizes[0];               // 262144*128
    const int n4 = n >> 2;                    // divisible by 4

    float*        gsum = (float*)d_ws;
    unsigned int* gcnt = (unsigned int*)((char*)d_ws + BINS * sizeof(float));

    // d_ws is re-poisoned to 0xAA before every timed launch — zero it (capturable)
    hipMemsetAsync(d_ws, 0, BINS * (sizeof(float) + sizeof(unsigned int)), stream);

    const int threads = 256;
    const int blocks  = 2048;   // 16 float4/thread -> 4 bulk groups
    ghm_partial<<<blocks, threads, 0, stream>>>(
        (const float4*)p, (const float4*)t, gsum, gcnt, n4);

    ghm_finalize<<<1, 64, 0, stream>>>(gsum, gcnt, (float*)d_out);
}

// Round 3
// 628.429 us; speedup vs baseline: 1.0066x; 1.0066x over previous
//
#include <hip/hip_runtime.h>

#define BINS 10

// R7: resubmit of R6 (container acquisition failed twice — no kernel signal).
// Design: R4's register/ballot binning (R5's LDS-atomic histogram measured
// ~4 cyc/lane on the DS atomic unit -> 290us floor; permanently rejected).
// Changes vs R4 baseline (114us kernel, Occupancy 52%, VALUBusy 29%, HBM 15%
// -> latency-bound):
//  1. __launch_bounds__(256, 8): 8 blocks/CU resident (grid 2048 = 8 x 256 CU),
//     32 waves/CU, doubling latency hiding. VGPR=24 fits the budget easily.
//  2. finalize fused into the last block via device-scope ticket (one fewer
//     dispatch). No block ever waits on another -> no hang possible.

__device__ __forceinline__ void elem(float p, float t,
                                     float* __restrict__ sb,
                                     unsigned int* __restrict__ cw)
{
    float g  = fabsf(p - t);
    float l2 = __log2f(1.0f - g);     // bce = -ln2*log2(1-g); fold -ln2 at end
    int   bi = (int)(g * 10.0f);      // g in (0.01,0.99): bi in [0,9]
#pragma unroll
    for (int b = 0; b < BINS; ++b) {
        bool hit = (bi == b);                   // one v_cmp -> sgpr pair
        unsigned long long m = __ballot(hit);   // reuses the compare
        sb[b] += hit ? l2 : 0.0f;               // cndmask + add (VALU)
        cw[b] += (unsigned int)__popcll(m);     // scalar pipe (wave-uniform)
    }
}

__device__ __forceinline__ void proc4v(const float4 p, const float4 t,
                                       float* __restrict__ sb,
                                       unsigned int* __restrict__ cw)
{
    elem(p.x, t.x, sb, cw); elem(p.y, t.y, sb, cw);
    elem(p.z, t.z, sb, cw); elem(p.w, t.w, sb, cw);
}

__global__ __launch_bounds__(256, 8) void ghm_fused(
    const float4* __restrict__ p4,
    const float4* __restrict__ t4,
    float* __restrict__ gsum,          // [BINS] floats in d_ws
    unsigned int* __restrict__ gcnt,   // [BINS] uints in d_ws
    unsigned int* __restrict__ ticket, // 1 uint in d_ws (zeroed by memset)
    float* __restrict__ out,
    int n4)
{
    float        sb[BINS];
    unsigned int cw[BINS];
#pragma unroll
    for (int b = 0; b < BINS; ++b) { sb[b] = 0.0f; cw[b] = 0u; }

    const int tid    = threadIdx.x;
    const int start  = blockIdx.x * blockDim.x + tid;
    const int stride = gridDim.x * blockDim.x;
    const int ngrp   = n4 / (4 * stride);   // 4 at 2048x256, n4 = 2^23

    // Bulk-load groups: 8 interleaved dwordx4 loads (128 B/thread in flight),
    // then a scheduling fence so the compiler cannot sink loads into compute.
    int i = start;
    for (int grp = 0; grp < ngrp; ++grp, i += 4 * stride) {
        float4 P0 = p4[i];
        float4 T0 = t4[i];
        float4 P1 = p4[i + stride];
        float4 T1 = t4[i + stride];
        float4 P2 = p4[i + 2 * stride];
        float4 T2 = t4[i + 2 * stride];
        float4 P3 = p4[i + 3 * stride];
        float4 T3 = t4[i + 3 * stride];
        __builtin_amdgcn_sched_barrier(0);  // loads above, compute below
        proc4v(P0, T0, sb, cw);
        proc4v(P1, T1, sb, cw);
        proc4v(P2, T2, sb, cw);
        proc4v(P3, T3, sb, cw);
    }
    // tail: any remaining float4s (n4 not divisible by 4*stride)
    for (int j = start + ngrp * 4 * stride; j < n4; j += stride) {
        float4 p = p4[j], t = t4[j];
        proc4v(p, t, sb, cw);
    }

    // -------- epilogue: wave reduce -> LDS -> one global atomic/bin/block ----
    __shared__ float        redS[BINS];
    __shared__ unsigned int redC[BINS];
    if (tid < BINS) { redS[tid] = 0.0f; redC[tid] = 0u; }
    __syncthreads();

    const int lane = tid & 63;
#pragma unroll
    for (int b = 0; b < BINS; ++b) {
        float s = sb[b];
#pragma unroll
        for (int off = 32; off > 0; off >>= 1) s += __shfl_down(s, off);
        if (lane == 0) {
            atomicAdd(&redS[b], s);
            atomicAdd(&redC[b], cw[b]);   // cw is wave-uniform (ballot-derived)
        }
    }
    __syncthreads();
    if (tid < BINS) {
        atomicAdd(&gsum[tid], redS[tid]);
        atomicAdd(&gcnt[tid], redC[tid]);
    }

    // -------- fused finalize: last block through the ticket does the math ----
    __threadfence();  // make this block's gsum/gcnt atomics device-visible
    __shared__ int isLast;
    if (tid == 0) {
        unsigned int done = atomicAdd(ticket, 1u);   // device-scope, serializes
        isLast = (done == (unsigned int)(gridDim.x - 1)) ? 1 : 0;
    }
    __syncthreads();
    if (isLast && tid == 0) {
        __threadfence();  // acquire side: order reads after the ticket atomic
        volatile float*        vs = (volatile float*)gsum;
        volatile unsigned int* vc = (volatile unsigned int*)gcnt;
        float        s[BINS];
        unsigned int c[BINS];
#pragma unroll
        for (int b = 0; b < BINS; ++b) { s[b] = vs[b]; c[b] = vc[b]; }
        int n = 0;
#pragma unroll
        for (int b = 0; b < BINS; ++b) n += (c[b] > 0u) ? 1 : 0;
        float nn  = (float)(n > 0 ? n : 1);
        float acc = 0.0f;
#pragma unroll
        for (int b = 0; b < BINS; ++b) {
            if (c[b] > 0u)
                acc += s[b] / ((float)c[b] * nn);   // counts < 2^24: exact
        }
        out[0] = -0.6931471805599453f * acc;  // fold -ln(2) from log2 domain
    }
}

extern "C" void kernel_launch(void* const* d_in, const int* in_sizes, int n_in,
                              void* d_out, int out_size, void* d_ws, size_t ws_size,
                              hipStream_t stream)
{
    const float* p = (const float*)d_in[0];   // inputs (probabilities)
    const float* t = (const float*)d_in[1];   // targets (0/1 floats)
    const int n  = in_sizes[0];               // 262144*128
    const int n4 = n >> 2;                    // divisible by 4

    float*        gsum   = (float*)d_ws;
    unsigned int* gcnt   = (unsigned int*)((char*)d_ws + BINS * sizeof(float));
    unsigned int* ticket = (unsigned int*)((char*)d_ws +
                            BINS * (sizeof(float) + sizeof(unsigned int)));

    // d_ws is re-poisoned to 0xAA before every timed launch — zero the
    // accumulators AND the ticket (capturable async memset, 84 bytes)
    hipMemsetAsync(d_ws, 0,
                   BINS * (sizeof(float) + sizeof(unsigned int)) + sizeof(unsigned int),
                   stream);

    const int threads = 256;
    const int blocks  = 2048;   // 8 blocks/CU resident, 16 float4/thread
    ghm_fused<<<blocks, threads, 0, stream>>>(
        (const float4*)p, (const float4*)t, gsum, gcnt, ticket,
        (float*)d_out, n4);
}

// Round 4
// 290.155 us; speedup vs baseline: 2.1802x; 2.1658x over previous
//
#include <hip/hip_runtime.h>

#define BINS 10

// R8: exact revert to the R4 two-kernel structure. R7's fused finalize added a
// per-wave __threadfence() (device-scope L2 wb/inv) whose serialized tail cost
// ~330us — counters showed compute time unchanged (VALU-busy time 34us ==
// R4's 33us) — ticket+fence pattern permanently rejected.
// Single change vs R4: __launch_bounds__(256, 8) — R4 ran 4 blocks/CU
// (Occupancy 52%) and was latency-bound (VALUBusy 29%, HBM 15%); VGPR=24
// leaves 8 blocks/CU reachable. This round isolates the occupancy lever.

__device__ __forceinline__ void elem(float p, float t,
                                     float* __restrict__ sb,
                                     unsigned int* __restrict__ cw)
{
    float g  = fabsf(p - t);
    float l2 = __log2f(1.0f - g);     // bce = -ln2*log2(1-g); fold -ln2 at end
    int   bi = (int)(g * 10.0f);      // g in (0.01,0.99): bi in [0,9]
#pragma unroll
    for (int b = 0; b < BINS; ++b) {
        bool hit = (bi == b);                   // one v_cmp -> sgpr pair
        unsigned long long m = __ballot(hit);   // reuses the compare
        sb[b] += hit ? l2 : 0.0f;               // cndmask + add (VALU)
        cw[b] += (unsigned int)__popcll(m);     // scalar pipe (wave-uniform)
    }
}

__device__ __forceinline__ void proc4v(const float4 p, const float4 t,
                                       float* __restrict__ sb,
                                       unsigned int* __restrict__ cw)
{
    elem(p.x, t.x, sb, cw); elem(p.y, t.y, sb, cw);
    elem(p.z, t.z, sb, cw); elem(p.w, t.w, sb, cw);
}

__global__ __launch_bounds__(256, 8) void ghm_partial(
    const float4* __restrict__ p4,
    const float4* __restrict__ t4,
    float* __restrict__ gsum,          // [BINS] floats in d_ws
    unsigned int* __restrict__ gcnt,   // [BINS] uints in d_ws
    int n4)
{
    float        sb[BINS];
    unsigned int cw[BINS];
#pragma unroll
    for (int b = 0; b < BINS; ++b) { sb[b] = 0.0f; cw[b] = 0u; }

    const int tid    = threadIdx.x;
    const int start  = blockIdx.x * blockDim.x + tid;
    const int stride = gridDim.x * blockDim.x;
    const int ngrp   = n4 / (4 * stride);   // 4 at 2048x256, n4 = 2^23

    // Bulk-load groups: 8 interleaved dwordx4 loads (128 B/thread in flight),
    // then a scheduling fence so the compiler cannot sink loads into compute.
    int i = start;
    for (int grp = 0; grp < ngrp; ++grp, i += 4 * stride) {
        float4 P0 = p4[i];
        float4 T0 = t4[i];
        float4 P1 = p4[i + stride];
        float4 T1 = t4[i + stride];
        float4 P2 = p4[i + 2 * stride];
        float4 T2 = t4[i + 2 * stride];
        float4 P3 = p4[i + 3 * stride];
        float4 T3 = t4[i + 3 * stride];
        __builtin_amdgcn_sched_barrier(0);  // loads above, compute below
        proc4v(P0, T0, sb, cw);
        proc4v(P1, T1, sb, cw);
        proc4v(P2, T2, sb, cw);
        proc4v(P3, T3, sb, cw);
    }
    // tail: any remaining float4s (n4 not divisible by 4*stride)
    for (int j = start + ngrp * 4 * stride; j < n4; j += stride) {
        float4 p = p4[j], t = t4[j];
        proc4v(p, t, sb, cw);
    }

    // -------- epilogue: wave reduce -> LDS -> one global atomic/bin/block ----
    __shared__ float        redS[BINS];
    __shared__ unsigned int redC[BINS];
    if (tid < BINS) { redS[tid] = 0.0f; redC[tid] = 0u; }
    __syncthreads();

    const int lane = tid & 63;
#pragma unroll
    for (int b = 0; b < BINS; ++b) {
        float s = sb[b];
#pragma unroll
        for (int off = 32; off > 0; off >>= 1) s += __shfl_down(s, off);
        if (lane == 0) {
            atomicAdd(&redS[b], s);
            atomicAdd(&redC[b], cw[b]);   // cw is wave-uniform (ballot-derived)
        }
    }
    __syncthreads();
    if (tid < BINS) {
        atomicAdd(&gsum[tid], redS[tid]);
        atomicAdd(&gcnt[tid], redC[tid]);
    }
}

__global__ void ghm_finalize(const float* __restrict__ gsum,
                             const unsigned int* __restrict__ gcnt,
                             float* __restrict__ out)
{
    if (threadIdx.x == 0 && blockIdx.x == 0) {
        int n = 0;
#pragma unroll
        for (int b = 0; b < BINS; ++b) n += (gcnt[b] > 0u) ? 1 : 0;
        float nn = (float)(n > 0 ? n : 1);
        float acc = 0.0f;
#pragma unroll
        for (int b = 0; b < BINS; ++b) {
            if (gcnt[b] > 0u)
                acc += gsum[b] / ((float)gcnt[b] * nn);  // counts < 2^24: exact
        }
        out[0] = -0.6931471805599453f * acc;   // fold -ln(2) from log2 domain
    }
}

extern "C" void kernel_launch(void* const* d_in, const int* in_sizes, int n_in,
                              void* d_out, int out_size, void* d_ws, size_t ws_size,
                              hipStream_t stream)
{
    const float* p = (const float*)d_in[0];   // inputs (probabilities)
    const float* t = (const float*)d_in[1];   // targets (0/1 floats)
    const int n  = in_sizes[0];               // 262144*128
    const int n4 = n >> 2;                    // divisible by 4

    float*        gsum = (float*)d_ws;
    unsigned int* gcnt = (unsigned int*)((char*)d_ws + BINS * sizeof(float));

    // d_ws is re-poisoned to 0xAA before every timed launch — zero it (capturable)
    hipMemsetAsync(d_ws, 0, BINS * (sizeof(float) + sizeof(unsigned int)), stream);

    const int threads = 256;
    const int blocks  = 2048;   // 16 float4/thread -> 4 bulk groups
    ghm_partial<<<blocks, threads, 0, stream>>>(
        (const float4*)p, (const float4*)t, gsum, gcnt, n4);

    ghm_finalize<<<1, 64, 0, stream>>>(gsum, gcnt, (float*)d_out);
}